// Round 1
// 625.707 us; speedup vs baseline: 1.4292x; 1.4292x over previous
//
#include <hip/hip_runtime.h>
#include <hip/hip_bf16.h>

typedef __hip_bfloat16 bf16;

// Problem constants
constexpr int Nn  = 4;
constexpr int Ci  = 256;
constexpr int Cc  = 64;
constexpr int Hh  = 128;
constexpr int Ww  = 128;
constexpr int HWh = Hh * Ww;
constexpr int Hl  = 64;
constexpr int Wl  = 64;
constexpr int HWl = Hl * Wl;
constexpr int K2L = 25;
constexpr int K2H = 9;

// Output element offsets (in output elements): [mask | hr_out | lr_out]
constexpr size_t OFF_MASK = 0;
constexpr size_t OFF_HR   = (size_t)Nn * K2L * HWh;            // 1,638,400
constexpr size_t OFF_LR   = OFF_HR + (size_t)Nn * Ci * HWh;    // 18,415,616

// Arena A (inside out_lr region; min capacity 8,388,608 f32 in bf16 mode)
constexpr size_t A_CHF    = 0;        // 4,194,304  [s2-s5]
constexpr size_t A_MLRHR  = 0;        // 1,638,400  [s6-s9]  (chf dead)
constexpr size_t A_MLRLL  = 1700000;  //   409,600  [s7-s9]
constexpr size_t A_CLFE2  = 2200000;  //   147,456  [s7-s11]
constexpr size_t A_MLRS1  = 2400000;  // 1,638,400  [s8-s9]
constexpr size_t A_MHR2S  = 4100000;  //   589,824  [s12-s14]
constexpr size_t A_WHR    = 7800000;  // 16,384 weights, live s1-s7
constexpr size_t A_WLR    = 7820000;  // 16,384
constexpr size_t A_WENC   = 7840000;  // 14,400
constexpr size_t A_WENC2  = 7860000;  //  5,184
constexpr size_t A_BHR    = 7870000;  // 64
constexpr size_t A_BLR    = 7870100;  // 64
constexpr size_t A_BENC   = 7870200;  // 64
constexpr size_t A_BENC2  = 7870300;  // 64   -> top 7,870,364 < 8,388,608 OK

// Arena B (inside out_hr region)
constexpr size_t B_CLF    = 0;        // 1,048,576  [s2-s7]
constexpr size_t B_CHF2   = 1100000;  // 4,194,304  [s5-s6]
constexpr size_t B_MHRHR  = 5300000;  //   589,824  [s3-s11]
constexpr size_t B_MHRSM  = 5900000;  //   589,824  [s4-s5]  -> top 6,489,824 OK
constexpr size_t B_MLR    = 0;        // 1,638,400  [s9-s10]
constexpr size_t B_MHR2   = 1700000;  //   589,824  [s11-s12]

__device__ __forceinline__ float tofloat(float v) { return v; }
__device__ __forceinline__ float tofloat(bf16 v) { return __bfloat162float(v); }

template<typename T> __device__ __forceinline__ T fromfloat(float v);
template<> __device__ __forceinline__ float fromfloat<float>(float v) { return v; }
template<> __device__ __forceinline__ bf16  fromfloat<bf16>(float v)  { return __float2bfloat16(v); }

// f32 scratch pointer inside an output region whose byte address depends on
// the detected output dtype (region offsets are in OUTPUT elements).
__device__ __forceinline__ float* scrp(void* d, int f32, size_t reg, size_t off) {
  float* b = f32 ? ((float*)d + reg) : (float*)((bf16*)d + reg);
  return b + off;
}

// ---------------------------------------------------------------------------
// dtype detector: bf16 data -> all sane values; f32 data read as bf16 ->
// ~half the half-words are |v|>1000 or NaN. flag=1 means f32 mode.
// ---------------------------------------------------------------------------
__global__ void detect_dtype(const void* feat, int* flag) {
  __shared__ int s;
  if (threadIdx.x == 0) s = 0;
  __syncthreads();
  unsigned short b = ((const unsigned short*)feat)[threadIdx.x];
  float v = __uint_as_float(((unsigned int)b) << 16);
  if (!(fabsf(v) < 1000.0f)) atomicOr(&s, 1);
  __syncthreads();
  if (threadIdx.x == 0) *flag = s;
}

// ---------------------------------------------------------------------------
// Weight prep (dtype-dual)
// ---------------------------------------------------------------------------
template<typename T>
__device__ void prep_body(const T* hw, const T* hb, const T* lw, const T* lb,
                          const T* ew, const T* eb, const T* e2w, const T* e2b,
                          float* whr, float* wlr, float* wenc, float* wenc2,
                          float* bhr, float* blr, float* benc, float* benc2) {
  int tid = blockIdx.x * 256 + threadIdx.x, nt = gridDim.x * 256;
  for (int i = tid; i < Cc * Ci; i += nt) {
    int co = i / Ci, ci = i % Ci;
    whr[ci * Cc + co] = tofloat(hw[i]);
    wlr[ci * Cc + co] = tofloat(lw[i]);
  }
  for (int i = tid; i < K2L * Cc * 9; i += nt) {
    int ko = i / (Cc * 9), r = i % (Cc * 9), ci = r / 9, k = r % 9;
    wenc[(ci * K2L + ko) * 9 + k] = tofloat(ew[i]);
  }
  for (int i = tid; i < K2H * Cc * 9; i += nt) {
    int ko = i / (Cc * 9), r = i % (Cc * 9), ci = r / 9, k = r % 9;
    wenc2[(ci * K2H + ko) * 9 + k] = tofloat(e2w[i]);
  }
  if (tid < Cc)  { bhr[tid] = tofloat(hb[tid]); blr[tid] = tofloat(lb[tid]); }
  if (tid < K2L) benc[tid]  = tofloat(eb[tid]);
  if (tid < K2H) benc2[tid] = tofloat(e2b[tid]);
}

__global__ void prep_weights(const int* flag, void* dout,
                             const void* hw, const void* hb, const void* lw, const void* lb,
                             const void* ew, const void* eb, const void* e2w, const void* e2b) {
  int f32 = *flag;
  float* whr   = scrp(dout, f32, OFF_LR, A_WHR);
  float* wlr   = scrp(dout, f32, OFF_LR, A_WLR);
  float* wenc  = scrp(dout, f32, OFF_LR, A_WENC);
  float* wenc2 = scrp(dout, f32, OFF_LR, A_WENC2);
  float* bhr   = scrp(dout, f32, OFF_LR, A_BHR);
  float* blr   = scrp(dout, f32, OFF_LR, A_BLR);
  float* benc  = scrp(dout, f32, OFF_LR, A_BENC);
  float* benc2 = scrp(dout, f32, OFF_LR, A_BENC2);
  if (f32) prep_body<float>((const float*)hw, (const float*)hb, (const float*)lw, (const float*)lb,
                            (const float*)ew, (const float*)eb, (const float*)e2w, (const float*)e2b,
                            whr, wlr, wenc, wenc2, bhr, blr, benc, benc2);
  else     prep_body<bf16>((const bf16*)hw, (const bf16*)hb, (const bf16*)lw, (const bf16*)lb,
                           (const bf16*)ew, (const bf16*)eb, (const bf16*)e2w, (const bf16*)e2b,
                           whr, wlr, wenc, wenc2, bhr, blr, benc, benc2);
}

// ---------------------------------------------------------------------------
// 1x1 conv (dtype-dual input, f32 scratch output)
// 64 pixels/block (was 256): grid.x x4 -> 1024 blocks HR, 4 blocks/CU.
// ---------------------------------------------------------------------------
template<typename T>
__device__ void conv1x1_body(const T* __restrict__ in, const float* __restrict__ wt,
                             const float* __restrict__ bias, float* __restrict__ out, int P) {
  const int tid = threadIdx.x;
  const int n = blockIdx.y;
  const int pbase = blockIdx.x * 64 + (tid & 63);
  const int co0 = __builtin_amdgcn_readfirstlane((tid >> 6) << 4);
  const T* inp = in + (size_t)n * Ci * P + pbase;

  float acc[16];
  #pragma unroll
  for (int c = 0; c < 16; ++c) acc[c] = bias[co0 + c];

  #pragma unroll 4
  for (int ci = 0; ci < Ci; ++ci) {
    float v = tofloat(inp[(size_t)ci * P]);
    const float* wr = wt + ci * Cc + co0;
    #pragma unroll
    for (int c = 0; c < 16; ++c) acc[c] = fmaf(v, wr[c], acc[c]);
  }
  float* op = out + (size_t)n * Cc * P + pbase;
  #pragma unroll
  for (int c = 0; c < 16; ++c) op[(size_t)(co0 + c) * P] = acc[c];
}

__global__ __launch_bounds__(256) void conv1x1_k(const int* flag, void* dout, const void* in,
                                                 size_t w_off, size_t b_off,
                                                 size_t o_reg, size_t o_off, int P) {
  int f32 = __builtin_amdgcn_readfirstlane(*flag);
  const float* wt   = scrp(dout, f32, OFF_LR, w_off);
  const float* bias = scrp(dout, f32, OFF_LR, b_off);
  float* out        = scrp(dout, f32, o_reg, o_off);
  if (f32) conv1x1_body<float>((const float*)in, wt, bias, out, P);
  else     conv1x1_body<bf16>((const bf16*)in, wt, bias, out, P);
}

// ---------------------------------------------------------------------------
// 3x3 conv, pad=1 (f32 scratch in/out)
// KO split into KO/KOG groups across blockIdx.z -> 5x (KO=25) / 3x (KO=9)
// more blocks. Input tile re-staged per group (L2/L3-resident, HBM at 2.7%).
// ---------------------------------------------------------------------------
template<int KO, int KOG>
__global__ __launch_bounds__(256) void conv3x3_k(const int* flag, void* dout,
                                                 size_t i_reg, size_t i_off,
                                                 size_t w_off, size_t b_off,
                                                 size_t o_reg, size_t o_off, int hh, int ww) {
  const int f32 = __builtin_amdgcn_readfirstlane(*flag);
  const float* in   = scrp(dout, f32, i_reg, i_off);
  const float* wt   = scrp(dout, f32, OFF_LR, w_off);
  const float* bias = scrp(dout, f32, OFF_LR, b_off);
  float* out        = scrp(dout, f32, o_reg, o_off);

  constexpr int NG = KO / KOG;
  __shared__ float tile[16 * 18 * 18];
  const int tid = threadIdx.x;
  const int tx = tid & 15, ty = tid >> 4;
  const int bx = blockIdx.x * 16, by = blockIdx.y * 16;
  const int n = blockIdx.z / NG;
  const int ko0 = (blockIdx.z % NG) * KOG;

  float acc[KOG];
  #pragma unroll
  for (int ko = 0; ko < KOG; ++ko) acc[ko] = bias[ko0 + ko];

  for (int cc = 0; cc < Cc; cc += 16) {
    __syncthreads();
    for (int i = tid; i < 16 * 18 * 18; i += 256) {
      int ci = i / 324, r = i % 324, yy = r / 18, xx = r % 18;
      int gy = by + yy - 1, gx = bx + xx - 1;
      float v = 0.f;
      if (gy >= 0 && gy < hh && gx >= 0 && gx < ww)
        v = in[(((size_t)n * Cc + cc + ci) * hh + gy) * ww + gx];
      tile[i] = v;
    }
    __syncthreads();
    for (int ci = 0; ci < 16; ++ci) {
      float nb[9];
      #pragma unroll
      for (int dy = 0; dy < 3; ++dy)
        #pragma unroll
        for (int dx = 0; dx < 3; ++dx)
          nb[dy * 3 + dx] = tile[ci * 324 + (ty + dy) * 18 + tx + dx];
      const float* wr = wt + ((size_t)(cc + ci) * KO + ko0) * 9;
      #pragma unroll
      for (int ko = 0; ko < KOG; ++ko)
        #pragma unroll
        for (int k = 0; k < 9; ++k)
          acc[ko] = fmaf(wr[ko * 9 + k], nb[k], acc[ko]);
    }
  }
  const size_t ob = (((size_t)n * KO + ko0) * hh + by + ty) * ww + bx + tx;
  #pragma unroll
  for (int ko = 0; ko < KOG; ++ko) out[ob + (size_t)ko * hh * ww] = acc[ko];
}

// ---------------------------------------------------------------------------
// softmax over K2 channels; optional f32 scratch out; optional dual-dtype
// write to final output 0 (mask_lr_out). 128-thread blocks -> 512 blocks.
// ---------------------------------------------------------------------------
template<int K2>
__global__ __launch_bounds__(256) void softmax_k(const int* flag, void* dout,
                                                 size_t i_reg, size_t i_off,
                                                 int wf32, size_t o_reg, size_t o_off, int w0) {
  int f32 = __builtin_amdgcn_readfirstlane(*flag);
  const float* in = scrp(dout, f32, i_reg, i_off);
  const int p = blockIdx.x * blockDim.x + threadIdx.x;
  const int n = blockIdx.y;
  const float* ip = in + (size_t)n * K2 * HWh + p;
  float v[K2], m = -1e30f;
  #pragma unroll
  for (int k = 0; k < K2; ++k) { v[k] = ip[(size_t)k * HWh]; m = fmaxf(m, v[k]); }
  float s = 0.f;
  #pragma unroll
  for (int k = 0; k < K2; ++k) { v[k] = __expf(v[k] - m); s += v[k]; }
  const float inv = 1.0f / s;
  #pragma unroll
  for (int k = 0; k < K2; ++k) v[k] *= inv;

  if (wf32) {
    float* op = scrp(dout, f32, o_reg, o_off) + (size_t)n * K2 * HWh + p;
    #pragma unroll
    for (int k = 0; k < K2; ++k) op[(size_t)k * HWh] = v[k];
  }
  if (w0) {
    const size_t g = (size_t)n * K2 * HWh + p;
    if (f32) {
      float* o = (float*)dout;
      #pragma unroll
      for (int k = 0; k < K2; ++k) o[g + (size_t)k * HWh] = v[k];
    } else {
      bf16* o = (bf16*)dout;
      #pragma unroll
      for (int k = 0; k < K2; ++k) o[g + (size_t)k * HWh] = fromfloat<bf16>(v[k]);
    }
  }
}

// ---------------------------------------------------------------------------
// s=1 CARAFE fused residual: out = 2*feat - sum_{3x3} feat_pad * mask
// Mask loaded per-thread directly (coalesced, same values as old LDS stage).
// ---------------------------------------------------------------------------
template<typename FT, typename OT, int FINAL>
__device__ void carafe1_body(const FT* __restrict__ feat, const float* __restrict__ mask,
                             void* dout, size_t out_reg, float* outscr, int C, int CPB) {
  const int tid = threadIdx.x;
  const int tx = tid & 15, ty = tid >> 4;
  const int bx = blockIdx.x * 16, by = blockIdx.y * 16;
  const int numCG = C / CPB;
  const int n = blockIdx.z / numCG, cg = blockIdx.z % numCG;
  const int x = bx + tx, y = by + ty;

  float mv[9];
  #pragma unroll
  for (int k = 0; k < 9; ++k)
    mv[k] = mask[(((size_t)n * 9 + k) * Hh + y) * Ww + x];

  const int c0 = cg * CPB;
  for (int c = c0; c < c0 + CPB; ++c) {
    const FT* fp = feat + ((size_t)n * C + c) * HWh;
    float s = 0.f, center = 0.f;
    #pragma unroll
    for (int dy = -1; dy <= 1; ++dy)
      #pragma unroll
      for (int dx = -1; dx <= 1; ++dx) {
        int yy = y + dy, xx = x + dx;
        float fv = 0.f;
        if (yy >= 0 && yy < Hh && xx >= 0 && xx < Ww) fv = tofloat(fp[yy * Ww + xx]);
        if (dy == 0 && dx == 0) center = fv;
        s = fmaf(fv, mv[(dy + 1) * 3 + (dx + 1)], s);
      }
    float r = 2.f * center - s;
    const size_t li = ((size_t)n * C + c) * HWh + y * Ww + x;
    if (FINAL) ((OT*)dout)[out_reg + li] = fromfloat<OT>(r);
    else       outscr[li] = r;
  }
}

__global__ __launch_bounds__(256) void carafe1_scr_k(const int* flag, void* dout,
    size_t f_reg, size_t f_off, size_t m_reg, size_t m_off, size_t o_reg, size_t o_off,
    int C, int CPB) {
  int f32 = __builtin_amdgcn_readfirstlane(*flag);
  carafe1_body<float, float, 0>(scrp(dout, f32, f_reg, f_off), scrp(dout, f32, m_reg, m_off),
                                dout, 0, scrp(dout, f32, o_reg, o_off), C, CPB);
}

__global__ __launch_bounds__(256) void carafe1_io_k(const int* flag, void* dout, const void* feat,
    size_t m_reg, size_t m_off, size_t out_reg, int C, int CPB) {
  int f32 = __builtin_amdgcn_readfirstlane(*flag);
  const float* m = scrp(dout, f32, m_reg, m_off);
  if (f32) carafe1_body<float, float, 1>((const float*)feat, m, dout, out_reg, nullptr, C, CPB);
  else     carafe1_body<bf16, bf16, 1>((const bf16*)feat, m, dout, out_reg, nullptr, C, CPB);
}

// ---------------------------------------------------------------------------
// s=2 CARAFE upsample (k=5): feat 64x64 -> out 128x128
// Mask loaded per-thread directly (no 25.6KB LDS stage) -> LDS = 4.6KB only.
// ---------------------------------------------------------------------------
template<typename FT, typename MT, typename OT, int ADD, int FINAL>
__device__ void carafe2_body(const FT* __restrict__ feat, const MT* __restrict__ mask,
                             const float* __restrict__ addend, void* dout, size_t out_reg,
                             float* outscr, int C, int CPB) {
  __shared__ float ft[8][144];
  const int tid = threadIdx.x;
  const int tx = tid & 15, ty = tid >> 4;
  const int bx = blockIdx.x * 16, by = blockIdx.y * 16;
  const int numCG = C / CPB;
  const int n = blockIdx.z / numCG, cg = blockIdx.z % numCG;
  const int x = bx + tx, y = by + ty;

  float mv[25];
  #pragma unroll
  for (int k = 0; k < 25; ++k)
    mv[k] = tofloat(mask[(((size_t)n * 25 + k) * Hh + y) * Ww + x]);

  const int fy0 = (by >> 1) - 2, fx0 = (bx >> 1) - 2;
  const int fyb = (ty >> 1) + 2, fxb = (tx >> 1) + 2;
  const int c0 = cg * CPB;

  for (int cb = 0; cb < CPB; cb += 8) {
    const int lim = (CPB - cb < 8) ? (CPB - cb) : 8;
    __syncthreads();
    for (int i = tid; i < lim * 144; i += 256) {
      int cc = i / 144, r = i % 144, fy = r / 12, fx = r % 12;
      int gy = fy0 + fy, gx = fx0 + fx;
      float v = 0.f;
      if (gy >= 0 && gy < Hl && gx >= 0 && gx < Wl)
        v = tofloat(feat[((size_t)n * C + c0 + cb + cc) * HWl + gy * Wl + gx]);
      ft[cc][r] = v;
    }
    __syncthreads();
    for (int cc = 0; cc < lim; ++cc) {
      float s = 0.f;
      #pragma unroll
      for (int ki = 0; ki < 5; ++ki)
        #pragma unroll
        for (int kj = 0; kj < 5; ++kj)
          s = fmaf(ft[cc][(fyb + ki - 2) * 12 + (fxb + kj - 2)], mv[ki * 5 + kj], s);
      const size_t li = (((size_t)n * C + c0 + cb + cc) * Hh + y) * Ww + x;
      float r = ADD ? (addend[li] + s) : s;
      if (FINAL) ((OT*)dout)[out_reg + li] = fromfloat<OT>(r);
      else       outscr[li] = r;
    }
  }
}

// s9: all f32 scratch, ADD
__global__ __launch_bounds__(256) void carafe2_scr_k(const int* flag, void* dout,
    size_t f_reg, size_t f_off, size_t m_reg, size_t m_off, size_t a_reg, size_t a_off,
    size_t o_reg, size_t o_off, int C, int CPB) {
  int f32 = __builtin_amdgcn_readfirstlane(*flag);
  carafe2_body<float, float, float, 1, 0>(scrp(dout, f32, f_reg, f_off), scrp(dout, f32, m_reg, m_off),
      scrp(dout, f32, a_reg, a_off), dout, 0, scrp(dout, f32, o_reg, o_off), C, CPB);
}

// s11: feat/addend/out scratch f32, mask = final output 0 (dtype by flag), ADD
__global__ __launch_bounds__(256) void carafe2_m0_k(const int* flag, void* dout,
    size_t f_reg, size_t f_off, size_t a_reg, size_t a_off, size_t o_reg, size_t o_off,
    int C, int CPB) {
  int f32 = __builtin_amdgcn_readfirstlane(*flag);
  const float* f = scrp(dout, f32, f_reg, f_off);
  const float* a = scrp(dout, f32, a_reg, a_off);
  float* o = scrp(dout, f32, o_reg, o_off);
  if (f32) carafe2_body<float, float, float, 1, 0>(f, (const float*)dout, a, dout, 0, o, C, CPB);
  else     carafe2_body<float, bf16, float, 1, 0>(f, (const bf16*)dout, a, dout, 0, o, C, CPB);
}

// s13: feat = input, mask = final output 0, out = final out_lr, no ADD
__global__ __launch_bounds__(256) void carafe2_io_k(const int* flag, void* dout, const void* feat,
    size_t out_reg, int C, int CPB) {
  int f32 = __builtin_amdgcn_readfirstlane(*flag);
  if (f32) carafe2_body<float, float, float, 0, 1>((const float*)feat, (const float*)dout,
      nullptr, dout, out_reg, nullptr, C, CPB);
  else     carafe2_body<bf16, bf16, bf16, 0, 1>((const bf16*)feat, (const bf16*)dout,
      nullptr, dout, out_reg, nullptr, C, CPB);
}

// ---------------------------------------------------------------------------
extern "C" void kernel_launch(void* const* d_in, const int* in_sizes, int n_in,
                              void* d_out, int out_size, void* d_ws, size_t ws_size,
                              hipStream_t stream) {
  const void* hr_feat = d_in[0];
  const void* lr_feat = d_in[1];
  int* flag = (int*)d_ws;  // only 4 bytes of ws used

  // 0. dtype detect (writes flag)
  detect_dtype<<<1, 256, 0, stream>>>(hr_feat, flag);
  // 1. weight prep -> arena A weight slots
  prep_weights<<<64, 256, 0, stream>>>(flag, d_out, d_in[2], d_in[3], d_in[4], d_in[5],
                                       d_in[6], d_in[7], d_in[8], d_in[9]);
  // 2. chf = conv1x1(hr_feat) -> A; clf = conv1x1(lr_feat) -> B  (64 px/block)
  conv1x1_k<<<dim3(HWh / 64, Nn), 256, 0, stream>>>(flag, d_out, hr_feat, A_WHR, A_BHR, OFF_LR, A_CHF, HWh);
  conv1x1_k<<<dim3(HWl / 64, Nn), 256, 0, stream>>>(flag, d_out, lr_feat, A_WLR, A_BLR, OFF_HR, B_CLF, HWl);
  // 3. mask_hr_hr = conv3x3(chf, enc2) -> B  (KO=9 split x3)
  conv3x3_k<K2H, 3><<<dim3(8, 8, Nn * 3), 256, 0, stream>>>(flag, d_out, OFF_LR, A_CHF, A_WENC2, A_BENC2, OFF_HR, B_MHRHR, Hh, Ww);
  // 4. mask_hr_init = softmax(mask_hr_hr) -> B
  softmax_k<K2H><<<dim3(HWh / 128, Nn), 128, 0, stream>>>(flag, d_out, OFF_HR, B_MHRHR, 1, OFF_HR, B_MHRSM, 0);
  // 5. chf2 = 2*chf - carafe_s1(chf, mask_hr_init) -> B  (CPB 64->16)
  carafe1_scr_k<<<dim3(8, 8, Nn * (Cc / 16)), 256, 0, stream>>>(flag, d_out, OFF_LR, A_CHF, OFF_HR, B_MHRSM, OFF_HR, B_CHF2, Cc, 16);
  // 6. mask_lr_hr = conv3x3(chf2, enc) -> A (chf dead)  (KO=25 split x5)
  conv3x3_k<K2L, 5><<<dim3(8, 8, Nn * 5), 256, 0, stream>>>(flag, d_out, OFF_HR, B_CHF2, A_WENC, A_BENC, OFF_LR, A_MLRHR, Hh, Ww);
  // 7. m_lr_ll = conv3x3(clf, enc) -> A ; clf_e2 = conv3x3(clf, enc2) -> A
  conv3x3_k<K2L, 5><<<dim3(4, 4, Nn * 5), 256, 0, stream>>>(flag, d_out, OFF_HR, B_CLF, A_WENC, A_BENC, OFF_LR, A_MLRLL, Hl, Wl);
  conv3x3_k<K2H, 3><<<dim3(4, 4, Nn * 3), 256, 0, stream>>>(flag, d_out, OFF_HR, B_CLF, A_WENC2, A_BENC2, OFF_LR, A_CLFE2, Hl, Wl);
  // 8. mask_lr_init = softmax(mask_lr_hr) -> A
  softmax_k<K2L><<<dim3(HWh / 128, Nn), 128, 0, stream>>>(flag, d_out, OFF_LR, A_MLRHR, 1, OFF_LR, A_MLRS1, 0);
  // 9. mask_lr = mask_lr_hr + carafe_s2(m_lr_ll, mask_lr_init) -> B  (CPB 25->5)
  carafe2_scr_k<<<dim3(8, 8, Nn * 5), 256, 0, stream>>>(flag, d_out, OFF_LR, A_MLRLL, OFF_LR, A_MLRS1,
                                                        OFF_LR, A_MLRHR, OFF_HR, B_MLR, K2L, 5);
  // 10. mask_lr_out = softmax(mask_lr) -> FINAL output 0 only
  softmax_k<K2L><<<dim3(HWh / 128, Nn), 128, 0, stream>>>(flag, d_out, OFF_HR, B_MLR, 0, 0, 0, 1);
  // 11. mask_hr = mask_hr_hr + carafe_s2(clf_e2, mask_lr_out) -> B  (CPB 9->3)
  carafe2_m0_k<<<dim3(8, 8, Nn * 3), 256, 0, stream>>>(flag, d_out, OFF_LR, A_CLFE2,
                                                       OFF_HR, B_MHRHR, OFF_HR, B_MHR2, K2H, 3);
  // 12. mask_hr_out = softmax(mask_hr) -> A (survives until s14)
  softmax_k<K2H><<<dim3(HWh / 128, Nn), 128, 0, stream>>>(flag, d_out, OFF_HR, B_MHR2, 1, OFF_LR, A_MHR2S, 0);
  // 14 (before 13!). hr_out = 2*hr_feat - carafe_s1(hr_feat, mask_hr_out) -> FINAL out_hr  (CPB 64->32)
  carafe1_io_k<<<dim3(8, 8, Nn * (Ci / 32)), 256, 0, stream>>>(flag, d_out, hr_feat,
                                                               OFF_LR, A_MHR2S, OFF_HR, Ci, 32);
  // 13 (last). lr_out = carafe_s2(lr_feat, mask_lr_out) -> FINAL out_lr (overwrites arena A)  (CPB 64->32)
  carafe2_io_k<<<dim3(8, 8, Nn * (Ci / 32)), 256, 0, stream>>>(flag, d_out, lr_feat, OFF_LR, Ci, 32);
}

// Round 2
// 575.738 us; speedup vs baseline: 1.5532x; 1.0868x over previous
//
#include <hip/hip_runtime.h>
#include <hip/hip_bf16.h>

typedef __hip_bfloat16 bf16;

// Problem constants
constexpr int Nn  = 4;
constexpr int Ci  = 256;
constexpr int Cc  = 64;
constexpr int Hh  = 128;
constexpr int Ww  = 128;
constexpr int HWh = Hh * Ww;
constexpr int Hl  = 64;
constexpr int Wl  = 64;
constexpr int HWl = Hl * Wl;
constexpr int K2L = 25;
constexpr int K2H = 9;

// Output element offsets (in output elements): [mask | hr_out | lr_out]
constexpr size_t OFF_MASK = 0;
constexpr size_t OFF_HR   = (size_t)Nn * K2L * HWh;            // 1,638,400
constexpr size_t OFF_LR   = OFF_HR + (size_t)Nn * Ci * HWh;    // 18,415,616

// Arena A (inside out_lr region; min capacity 8,388,608 f32 in bf16 mode)
constexpr size_t A_CHF    = 0;        // 4,194,304  [s2-s5]
constexpr size_t A_MLRHR  = 0;        // 1,638,400  [s6-s9]  (chf dead)
constexpr size_t A_MLRLL  = 1700000;  //   409,600  [s7-s9]
constexpr size_t A_CLFE2  = 2200000;  //   147,456  [s7-s11]
constexpr size_t A_MHRRAW = 4100000;  //   589,824  [s11-s14] raw mask_hr (softmax fused in s14)
constexpr size_t A_WHR    = 7800000;  // 16,384 weights, live s1-s7
constexpr size_t A_WLR    = 7820000;  // 16,384
constexpr size_t A_WENC   = 7840000;  // 14,400
constexpr size_t A_WENC2  = 7860000;  //  5,184
constexpr size_t A_BHR    = 7870000;  // 64
constexpr size_t A_BLR    = 7870100;  // 64
constexpr size_t A_BENC   = 7870200;  // 64
constexpr size_t A_BENC2  = 7870300;  // 64   -> top 7,870,364 < 8,388,608 OK

// Arena B (inside out_hr region)
constexpr size_t B_CLF    = 0;        // 1,048,576  [s2-s7]
constexpr size_t B_CHF2   = 1100000;  // 4,194,304  [s5-s6]
constexpr size_t B_MHRHR  = 5300000;  //   589,824  [s3-s11]  -> top 5,889,824 OK
constexpr size_t B_MLR    = 0;        // 1,638,400  [s9-s10]

__device__ __forceinline__ float tofloat(float v) { return v; }
__device__ __forceinline__ float tofloat(bf16 v) { return __bfloat162float(v); }

template<typename T> __device__ __forceinline__ T fromfloat(float v);
template<> __device__ __forceinline__ float fromfloat<float>(float v) { return v; }
template<> __device__ __forceinline__ bf16  fromfloat<bf16>(float v)  { return __float2bfloat16(v); }

// f32 scratch pointer inside an output region whose byte address depends on
// the detected output dtype (region offsets are in OUTPUT elements).
__device__ __forceinline__ float* scrp(void* d, int f32, size_t reg, size_t off) {
  float* b = f32 ? ((float*)d + reg) : (float*)((bf16*)d + reg);
  return b + off;
}

// ---------------------------------------------------------------------------
// dtype detector: bf16 data -> all sane values; f32 data read as bf16 ->
// ~half the half-words are |v|>1000 or NaN. flag=1 means f32 mode.
// ---------------------------------------------------------------------------
__global__ void detect_dtype(const void* feat, int* flag) {
  __shared__ int s;
  if (threadIdx.x == 0) s = 0;
  __syncthreads();
  unsigned short b = ((const unsigned short*)feat)[threadIdx.x];
  float v = __uint_as_float(((unsigned int)b) << 16);
  if (!(fabsf(v) < 1000.0f)) atomicOr(&s, 1);
  __syncthreads();
  if (threadIdx.x == 0) *flag = s;
}

// ---------------------------------------------------------------------------
// Weight prep (dtype-dual)
// ---------------------------------------------------------------------------
template<typename T>
__device__ void prep_body(const T* hw, const T* hb, const T* lw, const T* lb,
                          const T* ew, const T* eb, const T* e2w, const T* e2b,
                          float* whr, float* wlr, float* wenc, float* wenc2,
                          float* bhr, float* blr, float* benc, float* benc2) {
  int tid = blockIdx.x * 256 + threadIdx.x, nt = gridDim.x * 256;
  for (int i = tid; i < Cc * Ci; i += nt) {
    int co = i / Ci, ci = i % Ci;
    whr[ci * Cc + co] = tofloat(hw[i]);
    wlr[ci * Cc + co] = tofloat(lw[i]);
  }
  for (int i = tid; i < K2L * Cc * 9; i += nt) {
    int ko = i / (Cc * 9), r = i % (Cc * 9), ci = r / 9, k = r % 9;
    wenc[(ci * K2L + ko) * 9 + k] = tofloat(ew[i]);
  }
  for (int i = tid; i < K2H * Cc * 9; i += nt) {
    int ko = i / (Cc * 9), r = i % (Cc * 9), ci = r / 9, k = r % 9;
    wenc2[(ci * K2H + ko) * 9 + k] = tofloat(e2w[i]);
  }
  if (tid < Cc)  { bhr[tid] = tofloat(hb[tid]); blr[tid] = tofloat(lb[tid]); }
  if (tid < K2L) benc[tid]  = tofloat(eb[tid]);
  if (tid < K2H) benc2[tid] = tofloat(e2b[tid]);
}

__global__ void prep_weights(const int* flag, void* dout,
                             const void* hw, const void* hb, const void* lw, const void* lb,
                             const void* ew, const void* eb, const void* e2w, const void* e2b) {
  int f32 = *flag;
  float* whr   = scrp(dout, f32, OFF_LR, A_WHR);
  float* wlr   = scrp(dout, f32, OFF_LR, A_WLR);
  float* wenc  = scrp(dout, f32, OFF_LR, A_WENC);
  float* wenc2 = scrp(dout, f32, OFF_LR, A_WENC2);
  float* bhr   = scrp(dout, f32, OFF_LR, A_BHR);
  float* blr   = scrp(dout, f32, OFF_LR, A_BLR);
  float* benc  = scrp(dout, f32, OFF_LR, A_BENC);
  float* benc2 = scrp(dout, f32, OFF_LR, A_BENC2);
  if (f32) prep_body<float>((const float*)hw, (const float*)hb, (const float*)lw, (const float*)lb,
                            (const float*)ew, (const float*)eb, (const float*)e2w, (const float*)e2b,
                            whr, wlr, wenc, wenc2, bhr, blr, benc, benc2);
  else     prep_body<bf16>((const bf16*)hw, (const bf16*)hb, (const bf16*)lw, (const bf16*)lb,
                           (const bf16*)ew, (const bf16*)eb, (const bf16*)e2w, (const bf16*)e2b,
                           whr, wlr, wenc, wenc2, bhr, blr, benc, benc2);
}

// ---------------------------------------------------------------------------
// 1x1 conv (dtype-dual input, f32 scratch output)
// 64 pixels/block; CW output channels per wave; blockIdx.y = co-group.
// ---------------------------------------------------------------------------
template<typename T, int CW>
__device__ void conv1x1_body(const T* __restrict__ in, const float* __restrict__ wt,
                             const float* __restrict__ bias, float* __restrict__ out, int P) {
  const int tid = threadIdx.x;
  const int n = blockIdx.z;
  const int pbase = blockIdx.x * 64 + (tid & 63);
  const int co0 = __builtin_amdgcn_readfirstlane(blockIdx.y * 4 * CW + ((tid >> 6) * CW));
  const T* inp = in + (size_t)n * Ci * P + pbase;

  float acc[CW];
  #pragma unroll
  for (int c = 0; c < CW; ++c) acc[c] = bias[co0 + c];

  #pragma unroll 4
  for (int ci = 0; ci < Ci; ++ci) {
    float v = tofloat(inp[(size_t)ci * P]);
    const float* wr = wt + ci * Cc + co0;
    #pragma unroll
    for (int c = 0; c < CW; ++c) acc[c] = fmaf(v, wr[c], acc[c]);
  }
  float* op = out + (size_t)n * Cc * P + pbase;
  #pragma unroll
  for (int c = 0; c < CW; ++c) op[(size_t)(co0 + c) * P] = acc[c];
}

template<int CW>
__global__ __launch_bounds__(256) void conv1x1_k(const int* flag, void* dout, const void* in,
                                                 size_t w_off, size_t b_off,
                                                 size_t o_reg, size_t o_off, int P) {
  int f32 = __builtin_amdgcn_readfirstlane(*flag);
  const float* wt   = scrp(dout, f32, OFF_LR, w_off);
  const float* bias = scrp(dout, f32, OFF_LR, b_off);
  float* out        = scrp(dout, f32, o_reg, o_off);
  if (f32) conv1x1_body<float, CW>((const float*)in, wt, bias, out, P);
  else     conv1x1_body<bf16, CW>((const bf16*)in, wt, bias, out, P);
}

// ---------------------------------------------------------------------------
// 3x3 conv body, pad=1 (f32 scratch in/out); computes KOG of KO channels.
// ---------------------------------------------------------------------------
template<int KO, int KOG>
__device__ __forceinline__ void conv3x3_body(const float* __restrict__ in,
                                             const float* __restrict__ wt,
                                             const float* __restrict__ bias,
                                             float* __restrict__ out,
                                             int hh, int ww, int n, int ko0, float* tile) {
  const int tid = threadIdx.x;
  const int tx = tid & 15, ty = tid >> 4;
  const int bx = blockIdx.x * 16, by = blockIdx.y * 16;

  float acc[KOG];
  #pragma unroll
  for (int ko = 0; ko < KOG; ++ko) acc[ko] = bias[ko0 + ko];

  for (int cc = 0; cc < Cc; cc += 16) {
    __syncthreads();
    for (int i = tid; i < 16 * 18 * 18; i += 256) {
      int ci = i / 324, r = i % 324, yy = r / 18, xx = r % 18;
      int gy = by + yy - 1, gx = bx + xx - 1;
      float v = 0.f;
      if (gy >= 0 && gy < hh && gx >= 0 && gx < ww)
        v = in[(((size_t)n * Cc + cc + ci) * hh + gy) * ww + gx];
      tile[i] = v;
    }
    __syncthreads();
    for (int ci = 0; ci < 16; ++ci) {
      float nb[9];
      #pragma unroll
      for (int dy = 0; dy < 3; ++dy)
        #pragma unroll
        for (int dx = 0; dx < 3; ++dx)
          nb[dy * 3 + dx] = tile[ci * 324 + (ty + dy) * 18 + tx + dx];
      const float* wr = wt + ((size_t)(cc + ci) * KO + ko0) * 9;
      #pragma unroll
      for (int ko = 0; ko < KOG; ++ko)
        #pragma unroll
        for (int k = 0; k < 9; ++k)
          acc[ko] = fmaf(wr[ko * 9 + k], nb[k], acc[ko]);
    }
  }
  const size_t ob = (((size_t)n * KO + ko0) * hh + by + ty) * ww + bx + tx;
  #pragma unroll
  for (int ko = 0; ko < KOG; ++ko) out[ob + (size_t)ko * hh * ww] = acc[ko];
}

template<int KO, int KOG>
__global__ __launch_bounds__(256) void conv3x3_k(const int* flag, void* dout,
                                                 size_t i_reg, size_t i_off,
                                                 size_t w_off, size_t b_off,
                                                 size_t o_reg, size_t o_off, int hh, int ww) {
  const int f32 = __builtin_amdgcn_readfirstlane(*flag);
  const float* in   = scrp(dout, f32, i_reg, i_off);
  const float* wt   = scrp(dout, f32, OFF_LR, w_off);
  const float* bias = scrp(dout, f32, OFF_LR, b_off);
  float* out        = scrp(dout, f32, o_reg, o_off);

  constexpr int NG = KO / KOG;
  __shared__ float tile[16 * 18 * 18];
  const int n = blockIdx.z / NG;
  const int ko0 = (blockIdx.z % NG) * KOG;
  conv3x3_body<KO, KOG>(in, wt, bias, out, hh, ww, n, ko0, tile);
}

// s7 fused: clf -> enc(25ch) groups 0..4 and enc2(9ch) groups 5..7, 64x64.
__global__ __launch_bounds__(256) void conv3x3_dual_k(const int* flag, void* dout) {
  const int f32 = __builtin_amdgcn_readfirstlane(*flag);
  const float* in    = scrp(dout, f32, OFF_HR, B_CLF);
  const float* wenc  = scrp(dout, f32, OFF_LR, A_WENC);
  const float* benc  = scrp(dout, f32, OFF_LR, A_BENC);
  const float* wenc2 = scrp(dout, f32, OFF_LR, A_WENC2);
  const float* benc2 = scrp(dout, f32, OFF_LR, A_BENC2);
  float* out_ll  = scrp(dout, f32, OFF_LR, A_MLRLL);
  float* out_e2  = scrp(dout, f32, OFF_LR, A_CLFE2);

  __shared__ float tile[16 * 18 * 18];
  const int g = blockIdx.z % 8;
  const int n = blockIdx.z / 8;
  if (g < 5) conv3x3_body<K2L, 5>(in, wenc, benc, out_ll, Hl, Wl, n, g * 5, tile);
  else       conv3x3_body<K2H, 3>(in, wenc2, benc2, out_e2, Hl, Wl, n, (g - 5) * 3, tile);
}

// ---------------------------------------------------------------------------
// softmax over K2 channels -> final output 0 (mask_lr_out), dual-dtype.
// (All other softmaxes are fused into the consuming carafe kernels.)
// ---------------------------------------------------------------------------
template<int K2>
__global__ __launch_bounds__(256) void softmax_k(const int* flag, void* dout,
                                                 size_t i_reg, size_t i_off) {
  int f32 = __builtin_amdgcn_readfirstlane(*flag);
  const float* in = scrp(dout, f32, i_reg, i_off);
  const int p = blockIdx.x * blockDim.x + threadIdx.x;
  const int n = blockIdx.y;
  const float* ip = in + (size_t)n * K2 * HWh + p;
  float v[K2], m = -1e30f;
  #pragma unroll
  for (int k = 0; k < K2; ++k) { v[k] = ip[(size_t)k * HWh]; m = fmaxf(m, v[k]); }
  float s = 0.f;
  #pragma unroll
  for (int k = 0; k < K2; ++k) { v[k] = __expf(v[k] - m); s += v[k]; }
  const float inv = 1.0f / s;
  #pragma unroll
  for (int k = 0; k < K2; ++k) v[k] *= inv;

  const size_t g = (size_t)n * K2 * HWh + p;
  if (f32) {
    float* o = (float*)dout;
    #pragma unroll
    for (int k = 0; k < K2; ++k) o[g + (size_t)k * HWh] = v[k];
  } else {
    bf16* o = (bf16*)dout;
    #pragma unroll
    for (int k = 0; k < K2; ++k) o[g + (size_t)k * HWh] = fromfloat<bf16>(v[k]);
  }
}

// ---------------------------------------------------------------------------
// s=1 CARAFE fused residual: out = 2*feat - sum_{3x3} feat_pad * softmax?(mask)
// Mask loaded per-thread directly; SM=1 applies softmax in-register.
// ---------------------------------------------------------------------------
template<typename FT, typename OT, int FINAL, int SM>
__device__ void carafe1_body(const FT* __restrict__ feat, const float* __restrict__ mask,
                             void* dout, size_t out_reg, float* outscr, int C, int CPB) {
  const int tid = threadIdx.x;
  const int tx = tid & 15, ty = tid >> 4;
  const int bx = blockIdx.x * 16, by = blockIdx.y * 16;
  const int numCG = C / CPB;
  const int n = blockIdx.z / numCG, cg = blockIdx.z % numCG;
  const int x = bx + tx, y = by + ty;

  float mv[9];
  #pragma unroll
  for (int k = 0; k < 9; ++k)
    mv[k] = mask[(((size_t)n * 9 + k) * Hh + y) * Ww + x];
  if (SM) {
    float m = -1e30f;
    #pragma unroll
    for (int k = 0; k < 9; ++k) m = fmaxf(m, mv[k]);
    float s = 0.f;
    #pragma unroll
    for (int k = 0; k < 9; ++k) { mv[k] = __expf(mv[k] - m); s += mv[k]; }
    const float inv = 1.0f / s;
    #pragma unroll
    for (int k = 0; k < 9; ++k) mv[k] *= inv;
  }

  const int c0 = cg * CPB;
  for (int c = c0; c < c0 + CPB; ++c) {
    const FT* fp = feat + ((size_t)n * C + c) * HWh;
    float s = 0.f, center = 0.f;
    #pragma unroll
    for (int dy = -1; dy <= 1; ++dy)
      #pragma unroll
      for (int dx = -1; dx <= 1; ++dx) {
        int yy = y + dy, xx = x + dx;
        float fv = 0.f;
        if (yy >= 0 && yy < Hh && xx >= 0 && xx < Ww) fv = tofloat(fp[yy * Ww + xx]);
        if (dy == 0 && dx == 0) center = fv;
        s = fmaf(fv, mv[(dy + 1) * 3 + (dx + 1)], s);
      }
    float r = 2.f * center - s;
    const size_t li = ((size_t)n * C + c) * HWh + y * Ww + x;
    if (FINAL) ((OT*)dout)[out_reg + li] = fromfloat<OT>(r);
    else       outscr[li] = r;
  }
}

// s5: feat/mask f32 scratch, softmax fused, out scratch
__global__ __launch_bounds__(256) void carafe1_scr_k(const int* flag, void* dout,
    size_t f_reg, size_t f_off, size_t m_reg, size_t m_off, size_t o_reg, size_t o_off,
    int C, int CPB) {
  int f32 = __builtin_amdgcn_readfirstlane(*flag);
  carafe1_body<float, float, 0, 1>(scrp(dout, f32, f_reg, f_off), scrp(dout, f32, m_reg, m_off),
                                   dout, 0, scrp(dout, f32, o_reg, o_off), C, CPB);
}

// s14: feat = input hr_feat, mask raw f32 scratch (softmax fused), out final
__global__ __launch_bounds__(256) void carafe1_io_k(const int* flag, void* dout, const void* feat,
    size_t m_reg, size_t m_off, size_t out_reg, int C, int CPB) {
  int f32 = __builtin_amdgcn_readfirstlane(*flag);
  const float* m = scrp(dout, f32, m_reg, m_off);
  if (f32) carafe1_body<float, float, 1, 1>((const float*)feat, m, dout, out_reg, nullptr, C, CPB);
  else     carafe1_body<bf16, bf16, 1, 1>((const bf16*)feat, m, dout, out_reg, nullptr, C, CPB);
}

// ---------------------------------------------------------------------------
// s=2 CARAFE upsample (k=5): feat 64x64 -> out 128x128
// Mask loaded per-thread directly; SM=1 applies softmax in-register.
// ---------------------------------------------------------------------------
template<typename FT, typename MT, typename OT, int ADD, int FINAL, int SM>
__device__ void carafe2_body(const FT* __restrict__ feat, const MT* __restrict__ mask,
                             const float* __restrict__ addend, void* dout, size_t out_reg,
                             float* outscr, int C, int CPB) {
  __shared__ float ft[8][144];
  const int tid = threadIdx.x;
  const int tx = tid & 15, ty = tid >> 4;
  const int bx = blockIdx.x * 16, by = blockIdx.y * 16;
  const int numCG = C / CPB;
  const int n = blockIdx.z / numCG, cg = blockIdx.z % numCG;
  const int x = bx + tx, y = by + ty;

  float mv[25];
  #pragma unroll
  for (int k = 0; k < 25; ++k)
    mv[k] = tofloat(mask[(((size_t)n * 25 + k) * Hh + y) * Ww + x]);
  if (SM) {
    float m = -1e30f;
    #pragma unroll
    for (int k = 0; k < 25; ++k) m = fmaxf(m, mv[k]);
    float s = 0.f;
    #pragma unroll
    for (int k = 0; k < 25; ++k) { mv[k] = __expf(mv[k] - m); s += mv[k]; }
    const float inv = 1.0f / s;
    #pragma unroll
    for (int k = 0; k < 25; ++k) mv[k] *= inv;
  }

  const int fy0 = (by >> 1) - 2, fx0 = (bx >> 1) - 2;
  const int fyb = (ty >> 1) + 2, fxb = (tx >> 1) + 2;
  const int c0 = cg * CPB;

  for (int cb = 0; cb < CPB; cb += 8) {
    const int lim = (CPB - cb < 8) ? (CPB - cb) : 8;
    __syncthreads();
    for (int i = tid; i < lim * 144; i += 256) {
      int cc = i / 144, r = i % 144, fy = r / 12, fx = r % 12;
      int gy = fy0 + fy, gx = fx0 + fx;
      float v = 0.f;
      if (gy >= 0 && gy < Hl && gx >= 0 && gx < Wl)
        v = tofloat(feat[((size_t)n * C + c0 + cb + cc) * HWl + gy * Wl + gx]);
      ft[cc][r] = v;
    }
    __syncthreads();
    for (int cc = 0; cc < lim; ++cc) {
      float s = 0.f;
      #pragma unroll
      for (int ki = 0; ki < 5; ++ki)
        #pragma unroll
        for (int kj = 0; kj < 5; ++kj)
          s = fmaf(ft[cc][(fyb + ki - 2) * 12 + (fxb + kj - 2)], mv[ki * 5 + kj], s);
      const size_t li = (((size_t)n * C + c0 + cb + cc) * Hh + y) * Ww + x;
      float r = ADD ? (addend[li] + s) : s;
      if (FINAL) ((OT*)dout)[out_reg + li] = fromfloat<OT>(r);
      else       outscr[li] = r;
    }
  }
}

// s9: all f32 scratch, mask raw (softmax fused), ADD
__global__ __launch_bounds__(256) void carafe2_scr_k(const int* flag, void* dout,
    size_t f_reg, size_t f_off, size_t m_reg, size_t m_off, size_t a_reg, size_t a_off,
    size_t o_reg, size_t o_off, int C, int CPB) {
  int f32 = __builtin_amdgcn_readfirstlane(*flag);
  carafe2_body<float, float, float, 1, 0, 1>(scrp(dout, f32, f_reg, f_off), scrp(dout, f32, m_reg, m_off),
      scrp(dout, f32, a_reg, a_off), dout, 0, scrp(dout, f32, o_reg, o_off), C, CPB);
}

// s11: feat/addend/out scratch f32, mask = final output 0 (already softmaxed), ADD
__global__ __launch_bounds__(256) void carafe2_m0_k(const int* flag, void* dout,
    size_t f_reg, size_t f_off, size_t a_reg, size_t a_off, size_t o_reg, size_t o_off,
    int C, int CPB) {
  int f32 = __builtin_amdgcn_readfirstlane(*flag);
  const float* f = scrp(dout, f32, f_reg, f_off);
  const float* a = scrp(dout, f32, a_reg, a_off);
  float* o = scrp(dout, f32, o_reg, o_off);
  if (f32) carafe2_body<float, float, float, 1, 0, 0>(f, (const float*)dout, a, dout, 0, o, C, CPB);
  else     carafe2_body<float, bf16, float, 1, 0, 0>(f, (const bf16*)dout, a, dout, 0, o, C, CPB);
}

// s13: feat = input, mask = final output 0 (already softmaxed), out = final out_lr
__global__ __launch_bounds__(256) void carafe2_io_k(const int* flag, void* dout, const void* feat,
    size_t out_reg, int C, int CPB) {
  int f32 = __builtin_amdgcn_readfirstlane(*flag);
  if (f32) carafe2_body<float, float, float, 0, 1, 0>((const float*)feat, (const float*)dout,
      nullptr, dout, out_reg, nullptr, C, CPB);
  else     carafe2_body<bf16, bf16, bf16, 0, 1, 0>((const bf16*)feat, (const bf16*)dout,
      nullptr, dout, out_reg, nullptr, C, CPB);
}

// ---------------------------------------------------------------------------
extern "C" void kernel_launch(void* const* d_in, const int* in_sizes, int n_in,
                              void* d_out, int out_size, void* d_ws, size_t ws_size,
                              hipStream_t stream) {
  const void* hr_feat = d_in[0];
  const void* lr_feat = d_in[1];
  int* flag = (int*)d_ws;  // only 4 bytes of ws used

  // 0. dtype detect (writes flag)
  detect_dtype<<<1, 256, 0, stream>>>(hr_feat, flag);
  // 1. weight prep -> arena A weight slots
  prep_weights<<<64, 256, 0, stream>>>(flag, d_out, d_in[2], d_in[3], d_in[4], d_in[5],
                                       d_in[6], d_in[7], d_in[8], d_in[9]);
  // 2. chf = conv1x1(hr_feat) -> A (1024 blocks); clf = conv1x1(lr_feat) -> B (512 blocks)
  conv1x1_k<16><<<dim3(HWh / 64, 1, Nn), 256, 0, stream>>>(flag, d_out, hr_feat, A_WHR, A_BHR, OFF_LR, A_CHF, HWh);
  conv1x1_k<8><<<dim3(HWl / 64, 2, Nn), 256, 0, stream>>>(flag, d_out, lr_feat, A_WLR, A_BLR, OFF_HR, B_CLF, HWl);
  // 3. mask_hr_hr = conv3x3(chf, enc2) -> B  (KO=9 split x3)
  conv3x3_k<K2H, 3><<<dim3(8, 8, Nn * 3), 256, 0, stream>>>(flag, d_out, OFF_LR, A_CHF, A_WENC2, A_BENC2, OFF_HR, B_MHRHR, Hh, Ww);
  // 5. chf2 = 2*chf - carafe_s1(chf, softmax(mask_hr_hr)) -> B  [softmax fused]
  carafe1_scr_k<<<dim3(8, 8, Nn * (Cc / 16)), 256, 0, stream>>>(flag, d_out, OFF_LR, A_CHF, OFF_HR, B_MHRHR, OFF_HR, B_CHF2, Cc, 16);
  // 6. mask_lr_hr = conv3x3(chf2, enc) -> A (chf dead)  (KO=25 split x5)
  conv3x3_k<K2L, 5><<<dim3(8, 8, Nn * 5), 256, 0, stream>>>(flag, d_out, OFF_HR, B_CHF2, A_WENC, A_BENC, OFF_LR, A_MLRHR, Hh, Ww);
  // 7. m_lr_ll = conv3x3(clf, enc); clf_e2 = conv3x3(clf, enc2)  [one dual kernel, 512 blocks]
  conv3x3_dual_k<<<dim3(4, 4, Nn * 8), 256, 0, stream>>>(flag, d_out);
  // 9. mask_lr = mask_lr_hr + carafe_s2(m_lr_ll, softmax(mask_lr_hr)) -> B  [softmax fused]
  carafe2_scr_k<<<dim3(8, 8, Nn * 5), 256, 0, stream>>>(flag, d_out, OFF_LR, A_MLRLL, OFF_LR, A_MLRHR,
                                                        OFF_LR, A_MLRHR, OFF_HR, B_MLR, K2L, 5);
  // 10. mask_lr_out = softmax(mask_lr) -> FINAL output 0
  softmax_k<K2L><<<dim3(HWh / 128, Nn), 128, 0, stream>>>(flag, d_out, OFF_HR, B_MLR);
  // 11. mask_hr(raw) = mask_hr_hr + carafe_s2(clf_e2, mask_lr_out) -> A  (CPB=3)
  carafe2_m0_k<<<dim3(8, 8, Nn * 3), 256, 0, stream>>>(flag, d_out, OFF_LR, A_CLFE2,
                                                       OFF_HR, B_MHRHR, OFF_LR, A_MHRRAW, K2H, 3);
  // 14 (before 13!). hr_out = 2*hr_feat - carafe_s1(hr_feat, softmax(mask_hr)) -> FINAL out_hr
  carafe1_io_k<<<dim3(8, 8, Nn * (Ci / 32)), 256, 0, stream>>>(flag, d_out, hr_feat,
                                                               OFF_LR, A_MHRRAW, OFF_HR, Ci, 32);
  // 13 (last). lr_out = carafe_s2(lr_feat, mask_lr_out) -> FINAL out_lr (overwrites arena A)
  carafe2_io_k<<<dim3(8, 8, Nn * (Ci / 32)), 256, 0, stream>>>(flag, d_out, lr_feat, OFF_LR, Ci, 32);
}